// Round 14
// baseline (79.414 us; speedup 1.0000x reference)
//
#include <hip/hip_runtime.h>
#include <hip/hip_bf16.h>

// Problem: B=4, N=2048, C=256, H=4, d=64
// Pipeline: wconv -> gemm_qkv3(y=0:q,1:k,2:v) -> flash_attn_split<NS>
//           -> combine_xf (merge + Xf fast path; gamma-gated energy) ->
//           energy_reduce_softmax -> assemble_x (gamma!=0 only) -> gemm_proj
// flash: 64 q-rows/wave (4 q-tiles), K/V double-buffered, one barrier+vmcnt
// per k-tile, V fragments read once feeding all 4 q-tiles' PV.

typedef __attribute__((ext_vector_type(8))) short short8_t;
typedef __attribute__((ext_vector_type(4))) float f32x4;
typedef __attribute__((ext_vector_type(2))) unsigned u32x2;

#define NSEQ 2048

static __device__ __forceinline__ short f2bf(float f) {
  union { float f; unsigned u; } v; v.f = f;
  unsigned u = v.u;
  unsigned r = (u + 0x7FFFu + ((u >> 16) & 1u)) >> 16;
  return (short)r;
}
static __device__ __forceinline__ float bf2f(short s) {
  union { unsigned u; float f; } v;
  v.u = ((unsigned)(unsigned short)s) << 16;
  return v.f;
}
static __device__ __forceinline__ unsigned bcu(float f) {
  return __builtin_bit_cast(unsigned, f);
}
// pack two f32 into u32 of 2 bf16 (truncation) via v_perm_b32
static __device__ __forceinline__ unsigned pkbf(float lo, float hi) {
  return __builtin_amdgcn_perm(bcu(hi), bcu(lo), 0x07060302u);
}
// hardware RNE f32->bf16
static __device__ __forceinline__ short f2bf_hw(float f) {
  __hip_bfloat16 h = __float2bfloat16(f);
  return __builtin_bit_cast(short, h);
}
static __device__ __forceinline__ unsigned pk2bf_hw(float a, float b) {
  return ((unsigned)(unsigned short)__builtin_bit_cast(short, __float2bfloat16(b)) << 16) |
         (unsigned short)__builtin_bit_cast(short, __float2bfloat16(a));
}
static __device__ __forceinline__ f32x4 vmax4(f32x4 a, f32x4 b) {
  f32x4 r;
  r[0] = fmaxf(a[0], b[0]); r[1] = fmaxf(a[1], b[1]);
  r[2] = fmaxf(a[2], b[2]); r[3] = fmaxf(a[3], b[3]);
  return r;
}

// async global->LDS, 16B per lane; lds base must be wave-uniform.
static __device__ __forceinline__ void gload_lds16(const short* src, short* ldst) {
  __builtin_amdgcn_global_load_lds(
      (const __attribute__((address_space(1))) unsigned*)src,
      (__attribute__((address_space(3))) unsigned*)ldst, 16, 0, 0);
}

// ---------------------------------------------------------------- weights
__global__ __launch_bounds__(256) void wconv(
    const float* __restrict__ Wq, const float* __restrict__ Wkv,
    const float* __restrict__ Wp, short* __restrict__ Wqt,
    short* __restrict__ Wkvt, short* __restrict__ Wpt) {
  int tid = blockIdx.x * 256 + threadIdx.x;
  if (tid < 65536) {
    int n = tid >> 8, k = tid & 255;
    Wqt[tid] = f2bf(Wq[k * 256 + n]);
  } else if (tid < 196608) {
    int i = tid - 65536;
    int n = i >> 8, k = i & 255;
    Wkvt[i] = f2bf(Wkv[k * 512 + n]);
  } else {
    int i = tid - 196608;
    int n = i >> 8, k = i & 255;
    Wpt[i] = f2bf(Wp[k * 256 + n]);
  }
}

// --------------- QKV projection: LDS-staged A, 32 rows/block, 1 GEMM per block
__global__ __launch_bounds__(256) void gemm_qkv3(
    const float* __restrict__ t2, const float* __restrict__ t1,
    const short* __restrict__ Wqt, const short* __restrict__ Wkvt,
    short* __restrict__ Qb, short* __restrict__ Kb, short* __restrict__ Vtb) {
  __shared__ __align__(16) short ldsA[32 * 256];  // 16 KB, chunk-swizzled
  int tid = threadIdx.x;
  int m0 = blockIdx.x * 32;
  int y = blockIdx.y;
  const float* A = (y == 0) ? t2 : t1;

  const float* ap = A + (size_t)m0 * 256;
#pragma unroll
  for (int i = 0; i < 8; i++) {
    int idx = i * 256 + tid;
    int row = idx >> 6, c4 = idx & 63;
    f32x4 v = *(const f32x4*)(ap + (size_t)idx * 4);
    int ch8 = c4 >> 1, half = c4 & 1;
    int swz = ch8 ^ (row & 7);
    unsigned* dst = (unsigned*)&ldsA[row * 256 + swz * 8 + half * 4];
    dst[0] = pk2bf_hw(v[0], v[1]);
    dst[1] = pk2bf_hw(v[2], v[3]);
  }
  __syncthreads();

  int w = tid >> 6, l = tid & 63, lr = l & 15, lg = l >> 4;
  short8_t af[2][8];
#pragma unroll
  for (int mt = 0; mt < 2; mt++)
#pragma unroll
    for (int ks = 0; ks < 8; ks++)
      af[mt][ks] = *(const short8_t*)&ldsA[(mt * 16 + lr) * 256 +
                                           (((ks * 4 + lg) ^ (lr & 7)) * 8)];

  const short* Bt = (y == 0) ? Wqt : (y == 1 ? Wkvt : Wkvt + 65536);
  f32x4 acc[2][4] = {};
#pragma unroll
  for (int ct = 0; ct < 4; ct++) {
    const short* br = Bt + (size_t)(w * 64 + ct * 16 + lr) * 256 + lg * 8;
    short8_t bfr[8];
#pragma unroll
    for (int ks = 0; ks < 8; ks++) bfr[ks] = *(const short8_t*)(br + ks * 32);
    if (y < 2) {
#pragma unroll
      for (int ks = 0; ks < 8; ks++) {
        acc[0][ct] = __builtin_amdgcn_mfma_f32_16x16x32_bf16(af[0][ks], bfr[ks], acc[0][ct], 0, 0, 0);
        acc[1][ct] = __builtin_amdgcn_mfma_f32_16x16x32_bf16(af[1][ks], bfr[ks], acc[1][ct], 0, 0, 0);
      }
    } else {  // swapped operands for transposed V output
#pragma unroll
      for (int ks = 0; ks < 8; ks++) {
        acc[0][ct] = __builtin_amdgcn_mfma_f32_16x16x32_bf16(bfr[ks], af[0][ks], acc[0][ct], 0, 0, 0);
        acc[1][ct] = __builtin_amdgcn_mfma_f32_16x16x32_bf16(bfr[ks], af[1][ks], acc[1][ct], 0, 0, 0);
      }
    }
  }
  if (y < 2) {
    short* Ob = (y == 0) ? Qb : Kb;
#pragma unroll
    for (int ct = 0; ct < 4; ct++) {
      int c = w * 64 + ct * 16 + lr;
      int h = c >> 6, dd = c & 63;
#pragma unroll
      for (int mt = 0; mt < 2; mt++)
#pragma unroll
        for (int r = 0; r < 4; r++) {
          int m = m0 + mt * 16 + lg * 4 + r;
          int bb = m >> 11, n = m & 2047;
          Ob[(size_t)(((bb << 2) + h) * NSEQ + n) * 64 + dd] =
              f2bf_hw(acc[mt][ct][r]);
        }
    }
  } else {
#pragma unroll
    for (int ct = 0; ct < 4; ct++) {
      int c = w * 64 + ct * 16 + lg * 4;
#pragma unroll
      for (int mt = 0; mt < 2; mt++) {
        int m = m0 + mt * 16 + lr;
        int bb = m >> 11, n = m & 2047;
#pragma unroll
        for (int r = 0; r < 4; r++) {
          int cc = c + r;
          int h = cc >> 6, dd = cc & 63;
          Vtb[(size_t)(((bb << 2) + h) * 64 + dd) * NSEQ + n] =
              f2bf_hw(acc[mt][ct][r]);
        }
      }
    }
  }
}

// ---------------------------------------------------------- flash attention
// Swapped-operand, 64 q/wave (4 q-tiles): S^T = mfma(K, Q[j]), O^T = mfma(V, P[j]).
// K/V double-buffered; one barrier+vmcnt per k-tile. V fragments read once per
// iter feeding all 4 q-tiles; P slice serially reused per tile (wave-private).
template <int NS>
__global__ __launch_bounds__(256, 2) void flash_attn_split(
    const short* __restrict__ Qb, const short* __restrict__ Kb,
    const short* __restrict__ Vt, short* __restrict__ O0,
    short* __restrict__ O1, short* __restrict__ O2,
    short* __restrict__ O3, float* __restrict__ ML) {
  constexpr int KITER = 32 / NS;
  __shared__ __align__(16) short ldsK[2][4096];
  __shared__ __align__(16) short ldsV[2][4096];
  __shared__ __align__(16) short ldsP[4][1024];  // [w][16 q rows][64 kv], reused
  int tid = threadIdx.x;
  int w = tid >> 6, l = tid & 63, lr = l & 15, lg = l >> 4;
  int bh = blockIdx.y;
  int qt = blockIdx.x / NS, split = blockIdx.x % NS;
  int q0 = qt * 256 + w * 64;
  short8_t qf[4][2];
#pragma unroll
  for (int j = 0; j < 4; j++) {
    const short* qp = Qb + ((size_t)bh * NSEQ + q0 + j * 16 + lr) * 64 + lg * 8;
    qf[j][0] = *(const short8_t*)qp;
    qf[j][1] = *(const short8_t*)(qp + 32);
  }
  const short* kbase = Kb + (size_t)bh * NSEQ * 64;  // [n][64]
  const short* vbase = Vt + (size_t)bh * 64 * NSEQ;  // [d][2048]

  int r0 = tid >> 3, ch0 = (tid & 7) ^ (r0 & 7);
  int kb0 = split * KITER;
  const short* ksrc = kbase + (size_t)kb0 * 4096 + (size_t)r0 * 64 + ch0 * 8;
  const short* vsrc = vbase + (size_t)r0 * NSEQ + kb0 * 64 + ch0 * 8;
  short* ldKw0 = &ldsK[0][0] + w * 512;
  short* ldKw1 = &ldsK[1][0] + w * 512;
  short* ldVw0 = &ldsV[0][0] + w * 512;
  short* ldVw1 = &ldsV[1][0] + w * 512;

#define STAGE_KV(buf_, it_)                                 \
  {                                                         \
    const short* sk_ = ksrc + (size_t)(it_) * 4096;         \
    short* dk_ = (buf_) ? ldKw1 : ldKw0;                    \
    gload_lds16(sk_, dk_);                                  \
    gload_lds16(sk_ + 2048, dk_ + 2048);                    \
    const short* sv_ = vsrc + (size_t)(it_) * 64;           \
    short* dv_ = (buf_) ? ldVw1 : ldVw0;                    \
    gload_lds16(sv_, dv_);                                  \
    gload_lds16(sv_ + 32 * NSEQ, dv_ + 2048);               \
  }

  f32x4 o[4][4] = {};
  float osum[4], m2[4];
#pragma unroll
  for (int j = 0; j < 4; j++) { osum[j] = 0.f; m2[j] = -1e30f; }
  const float C = 0.125f * 1.44269504089f;  // SCALE * log2(e)

  int sw = lr & 7;
  int rdA = (lg ^ sw) * 8;
  int rdB = ((lg + 4) ^ sw) * 8;
  short* Pw = &ldsP[w][0];
  short* wrP = Pw + lr * 64 + (lg & 1) * 4;
  int chhi = lg >> 1;
  const short* pr0 = Pw + lr * 64 + (lg ^ sw) * 8;
  const short* pr1 = Pw + lr * 64 + ((4 + lg) ^ sw) * 8;

  STAGE_KV(0, 0);
  asm volatile("s_waitcnt vmcnt(0)" ::: "memory");
  __builtin_amdgcn_s_barrier();

  for (int i = 0; i < KITER; i++) {
    int buf = i & 1;
    if (i + 1 < KITER) STAGE_KV(buf ^ 1, i + 1);
    const short* lK = buf ? &ldsK[1][0] : &ldsK[0][0];
    const short* lV = buf ? &ldsV[1][0] : &ldsV[0][0];
    // S^T = K · Q for 4 q-tiles
    f32x4 s[4][4];  // [qtile][kv subtile]
    __builtin_amdgcn_s_setprio(1);
#pragma unroll
    for (int t = 0; t < 4; t++) {
      const short* kr = lK + (t * 16 + lr) * 64;
      short8_t kf0 = *(const short8_t*)(kr + rdA);
      short8_t kf1 = *(const short8_t*)(kr + rdB);
      f32x4 z = {0.f, 0.f, 0.f, 0.f};
#pragma unroll
      for (int j = 0; j < 4; j++) {
        f32x4 zj = __builtin_amdgcn_mfma_f32_16x16x32_bf16(kf0, qf[j][0], z, 0, 0, 0);
        s[j][t] = __builtin_amdgcn_mfma_f32_16x16x32_bf16(kf1, qf[j][1], zj, 0, 0, 0);
      }
    }
    __builtin_amdgcn_s_setprio(0);
    // per-tile softmax -> P slice -> hold P fragments
    short8_t pf[4][2];
#pragma unroll
    for (int j = 0; j < 4; j++) {
      f32x4 m4 = vmax4(vmax4(s[j][0], s[j][1]), vmax4(s[j][2], s[j][3]));
      float mx = fmaxf(fmaxf(m4[0], m4[1]), fmaxf(m4[2], m4[3]));
      mx = fmaxf(mx, __shfl_xor(mx, 16));
      mx = fmaxf(mx, __shfl_xor(mx, 32));
      mx *= C;
      float mn = fmaxf(m2[j], mx);
      if (__any(mn - m2[j] > 8.f)) {
        float a = __builtin_amdgcn_exp2f(m2[j] - mn);
        m2[j] = mn;
        osum[j] *= a;
#pragma unroll
        for (int dt = 0; dt < 4; dt++) o[j][dt] *= a;
      }
      float ps = 0.f;
#pragma unroll
      for (int t = 0; t < 4; t++) {
        float p0 = __builtin_amdgcn_exp2f(__builtin_fmaf(s[j][t][0], C, -m2[j]));
        float p1 = __builtin_amdgcn_exp2f(__builtin_fmaf(s[j][t][1], C, -m2[j]));
        float p2 = __builtin_amdgcn_exp2f(__builtin_fmaf(s[j][t][2], C, -m2[j]));
        float p3 = __builtin_amdgcn_exp2f(__builtin_fmaf(s[j][t][3], C, -m2[j]));
        ps += (p0 + p1) + (p2 + p3);
        u32x2 u = {pkbf(p0, p1), pkbf(p2, p3)};
        *(u32x2*)(wrP + ((2 * t + chhi) ^ sw) * 8) = u;
      }
      osum[j] += ps;
      pf[j][0] = *(const short8_t*)pr0;  // in-wave lgkm ordering
      pf[j][1] = *(const short8_t*)pr1;
    }
    // fused PV: V fragments read once, feed all 4 q-tiles
    __builtin_amdgcn_s_setprio(1);
#pragma unroll
    for (int dt = 0; dt < 4; dt++) {
      const short* vr = lV + (dt * 16 + lr) * 64;
      short8_t vf0 = *(const short8_t*)(vr + rdA);
      short8_t vf1 = *(const short8_t*)(vr + rdB);
#pragma unroll
      for (int j = 0; j < 4; j++) {
        o[j][dt] = __builtin_amdgcn_mfma_f32_16x16x32_bf16(vf0, pf[j][0], o[j][dt], 0, 0, 0);
        o[j][dt] = __builtin_amdgcn_mfma_f32_16x16x32_bf16(vf1, pf[j][1], o[j][dt], 0, 0, 0);
      }
    }
    __builtin_amdgcn_s_setprio(0);
    if (i + 1 < KITER) {
      asm volatile("s_waitcnt vmcnt(0)" ::: "memory");  // next K/V landed
      __builtin_amdgcn_s_barrier();
    }
  }
#undef STAGE_KV
  short* op = (split == 0) ? O0 : (split == 1) ? O1 : (split == 2) ? O2 : O3;
#pragma unroll
  for (int j = 0; j < 4; j++) {
    osum[j] += __shfl_xor(osum[j], 16);
    osum[j] += __shfl_xor(osum[j], 32);
    float inv = __builtin_amdgcn_rcpf(osum[j]);
#pragma unroll
    for (int dt = 0; dt < 4; dt++)
#pragma unroll
      for (int r = 0; r < 4; r++) {
        size_t drow = ((size_t)bh * 64 + dt * 16 + lg * 4 + r) * NSEQ;
        op[drow + q0 + j * 16 + lr] = f2bf_hw(o[j][dt][r] * inv);
      }
    if (lg == 0) {
      float2 v = {m2[j], osum[j]};
      *(float2*)&ML[((size_t)bh * NSEQ + q0 + j * 16 + lr) * 8 + split * 2] = v;
    }
  }
}

// -------- merge splits; gamma==0: write Xf directly (t2 + x + q residuals);
//          gamma!=0: write AOb + energy partials via MFMA.
template <int NS>
__global__ __launch_bounds__(256) void combine_xf(
    const short* __restrict__ O0, const short* __restrict__ O1,
    const short* __restrict__ O2, const short* __restrict__ O3,
    const float* __restrict__ ML, const float* __restrict__ gamma,
    const float* __restrict__ t2, const short* __restrict__ Qb,
    short* __restrict__ AOb, float* __restrict__ partials,
    short* __restrict__ Xf) {
  __shared__ __align__(16) short tileT[64][128];  // [dd][m], chunk-swizzled
  __shared__ f32x4 wcol[128];                     // per-column merge coeffs
  int tid = threadIdx.x;
  int b = blockIdx.y, kc = blockIdx.x;
  int h = kc >> 4, n0 = (kc & 15) * 128;
  int bh = (b << 2) + h;
  float g = gamma[0];
  if (tid < 128) {
    const float* ml = ML + ((size_t)bh * NSEQ + n0 + tid) * 8;
    f32x4 a = *(const f32x4*)ml;  // m0,s0,m1,s1
    f32x4 c;
    if (NS == 2) {
      float M = fmaxf(a[0], a[2]);
      float w0 = a[1] * __builtin_amdgcn_exp2f(a[0] - M);
      float w1 = a[3] * __builtin_amdgcn_exp2f(a[2] - M);
      float iv = __builtin_amdgcn_rcpf(w0 + w1);
      c[0] = w0 * iv; c[1] = w1 * iv; c[2] = 0.f; c[3] = 0.f;
    } else {
      f32x4 bq = *(const f32x4*)(ml + 4);  // m2,s2,m3,s3
      float M = fmaxf(fmaxf(a[0], a[2]), fmaxf(bq[0], bq[2]));
      float w0 = a[1] * __builtin_amdgcn_exp2f(a[0] - M);
      float w1 = a[3] * __builtin_amdgcn_exp2f(a[2] - M);
      float w2 = bq[1] * __builtin_amdgcn_exp2f(bq[0] - M);
      float w3 = bq[3] * __builtin_amdgcn_exp2f(bq[2] - M);
      float iv = __builtin_amdgcn_rcpf(w0 + w1 + w2 + w3);
      c[0] = w0 * iv; c[1] = w1 * iv; c[2] = w2 * iv; c[3] = w3 * iv;
    }
    wcol[tid] = c;
  }
  __syncthreads();
  {
    int chunk = tid & 15;   // 16B chunk within 128-col row (8 bf16)
    int rw = tid >> 4;      // 0..15
#pragma unroll
    for (int i = 0; i < 4; i++) {
      int row = rw + 16 * i;
      size_t gbase = ((size_t)bh * 64 + row) * NSEQ + n0 + chunk * 8;
      short8_t v0 = *(const short8_t*)(O0 + gbase);
      short8_t v1 = *(const short8_t*)(O1 + gbase);
      short8_t v2{}, v3{};
      if (NS == 4) {
        v2 = *(const short8_t*)(O2 + gbase);
        v3 = *(const short8_t*)(O3 + gbase);
      }
      short8_t comb;
#pragma unroll
      for (int j = 0; j < 8; j++) {
        f32x4 c = wcol[chunk * 8 + j];
        float val = bf2f(v0[j]) * c[0] + bf2f(v1[j]) * c[1];
        if (NS == 4) val += bf2f(v2[j]) * c[2] + bf2f(v3[j]) * c[3];
        comb[j] = f2bf_hw(val);
      }
      if (g != 0.f) *(short8_t*)(AOb + gbase) = comb;
      *(short8_t*)&tileT[row][(chunk ^ (row & 15)) * 8] = comb;
    }
  }
  __syncthreads();
  if (g == 0.f) {
    int nc = tid >> 1, half = tid & 1;
    int n = n0 + nc;
    int cidx = nc >> 3, jj = nc & 7;
    const float* t2p = t2 + ((size_t)b * NSEQ + n) * 256 + h * 64 + half * 32;
    const short* qp = Qb + ((size_t)bh * NSEQ + n) * 64 + half * 32;
    short* xfp = Xf + ((size_t)b * NSEQ + n) * 256 + h * 64 + half * 32;
#pragma unroll
    for (int i = 0; i < 4; i++) {
      int ddb = half * 32 + i * 8;
      f32x4 ta = *(const f32x4*)(t2p + i * 8);
      f32x4 tb = *(const f32x4*)(t2p + i * 8 + 4);
      short8_t q8 = *(const short8_t*)(qp + i * 8);
      short8_t r;
#pragma unroll
      for (int j = 0; j < 8; j++) {
        int dd = ddb + j;
        short xv = tileT[dd][((cidx ^ (dd & 15)) * 8) + jj];
        float t = (j < 4) ? ta[j] : tb[j - 4];
        r[j] = f2bf_hw(t + bf2f(xv) + bf2f(q8[j]));
      }
      *(short8_t*)(xfp + i * 8) = r;
    }
    return;
  }
  int w = tid >> 6, lr = tid & 15, lg = (tid & 63) >> 4;
  f32x4 acc[4] = {};
#pragma unroll
  for (int ks = 0; ks < 4; ks++) {
    short8_t af = *(const short8_t*)&tileT[w * 16 + lr][((ks * 4 + lg) ^ lr) * 8];
#pragma unroll
    for (int e = 0; e < 4; e++) {
      short8_t bf = *(const short8_t*)&tileT[e * 16 + lr][((ks * 4 + lg) ^ lr) * 8];
      acc[e] = __builtin_amdgcn_mfma_f32_16x16x32_bf16(af, bf, acc[e], 0, 0, 0);
    }
  }
  float* dst = partials + ((size_t)b * 64 + kc) * 4096;
#pragma unroll
  for (int e = 0; e < 4; e++)
#pragma unroll
    for (int r = 0; r < 4; r++)
      dst[(w * 16 + lg * 4 + r) * 64 + e * 16 + lr] = acc[e][r];
}

// -------------------------------- reduce partials over kc + channel softmax
__global__ __launch_bounds__(64) void energy_reduce_softmax(
    const float* __restrict__ partials, const float* __restrict__ gamma,
    float* __restrict__ attnc) {
  if (gamma[0] == 0.f) return;  // attnc unread when gamma == 0
  int row = blockIdx.x;  // b*64 + d
  int b = row >> 6, d = row & 63;
  int e = threadIdx.x;
  const float* src = partials + (size_t)b * 64 * 4096 + d * 64 + e;
  float s = 0.f;
#pragma unroll 8
  for (int kc = 0; kc < 64; kc++) s += src[(size_t)kc * 4096];
  float mx = s;
#pragma unroll
  for (int x = 1; x < 64; x <<= 1) mx = fmaxf(mx, __shfl_xor(mx, x, 64));
  float ev = __expf(s - mx);
  float sum = ev;
#pragma unroll
  for (int x = 1; x < 64; x <<= 1) sum += __shfl_xor(sum, x, 64);
  attnc[row * 64 + e] = ev / sum;
}

// ----------------------- lam apply + residuals (gamma != 0 slow path only)
__global__ __launch_bounds__(256) void assemble_x(
    const short* __restrict__ AOb, const float* __restrict__ attnc,
    const float* __restrict__ t2, const short* __restrict__ Qb,
    const float* __restrict__ gamma, short* __restrict__ Xf) {
  float g = gamma[0];
  if (g == 0.f) return;  // Xf already written by combine_xf fast path
  __shared__ f32x4 At4[1024];
  int b = blockIdx.y, tid = threadIdx.x;
  const f32x4* ac = (const f32x4*)(attnc + (size_t)b * 4096);
#pragma unroll
  for (int i = 0; i < 4; i++) At4[i * 256 + tid] = ac[i * 256 + tid];
  __syncthreads();
  int rowb = blockIdx.x * 256 + tid;
  int h = rowb >> 11, n = rowb & 2047;
  const short* xop = AOb + ((size_t)((b << 2) + h) * 64) * NSEQ + n;
  f32x4 xv[16];
#pragma unroll
  for (int i = 0; i < 16; i++) {
    f32x4 t;
    t[0] = bf2f(xop[(size_t)(4 * i + 0) * NSEQ]);
    t[1] = bf2f(xop[(size_t)(4 * i + 1) * NSEQ]);
    t[2] = bf2f(xop[(size_t)(4 * i + 2) * NSEQ]);
    t[3] = bf2f(xop[(size_t)(4 * i + 3) * NSEQ]);
    xv[i] = t;
  }
  const short* qp = Qb + ((size_t)b * 8192 + rowb) * 64;
  const float* t2p = t2 + ((size_t)b * 2048 + n) * 256 + h * 64;
  short* xfp = Xf + ((size_t)b * 2048 + n) * 256 + h * 64;
#pragma unroll
  for (int dd = 0; dd < 64; dd++) {
    f32x4 a = {0.f, 0.f, 0.f, 0.f};
#pragma unroll
    for (int j = 0; j < 16; j++) a += At4[dd * 16 + j] * xv[j];
    float o = (a[0] + a[1] + a[2] + a[3]) * g;
    float val = t2p[dd] + o + xv[dd >> 2][dd & 3] + bf2f(qp[dd]);
    xfp[dd] = f2bf_hw(val);
  }
}

// ------------------- final projection + bias (LDS-staged A, 16 rows/block)
__global__ __launch_bounds__(256) void gemm_proj(
    const short* __restrict__ Xf, const short* __restrict__ Wpt,
    const float* __restrict__ bias, float* __restrict__ out) {
  __shared__ __align__(16) short ldsA[16 * 256];  // 8 KB, chunk-swizzled
  int tid = threadIdx.x;
  int w = tid >> 6, l = tid & 63, lr = l & 15, lg = l >> 4;
  int m0 = blockIdx.x * 16;
#pragma unroll
  for (int i = 0; i < 2; i++) {
    int c = w * 128 + i * 64 + l;  // LDS chunk id (16B units)
    int row = c >> 5, ch = c & 31;
    int chs = (ch & 24) | ((ch & 7) ^ (row & 7));
    gload_lds16(Xf + (size_t)(m0 + row) * 256 + chs * 8,
                &ldsA[(w * 128 + i * 64) * 8]);
  }
  asm volatile("s_waitcnt vmcnt(0)" ::: "memory");
  __syncthreads();
  short8_t af[8];
#pragma unroll
  for (int ks = 0; ks < 8; ks++)
    af[ks] = *(const short8_t*)&ldsA[lr * 256 + (((ks * 4 + lg) ^ (lr & 7)) * 8)];
  f32x4 acc[4] = {};
#pragma unroll
  for (int ct = 0; ct < 4; ct++) {
    const short* br = Wpt + (size_t)(w * 64 + ct * 16 + lr) * 256 + lg * 8;
    short8_t bfr[8];
#pragma unroll
    for (int ks = 0; ks < 8; ks++) bfr[ks] = *(const short8_t*)(br + ks * 32);
#pragma unroll
    for (int ks = 0; ks < 8; ks++)
      acc[ct] = __builtin_amdgcn_mfma_f32_16x16x32_bf16(af[ks], bfr[ks], acc[ct], 0, 0, 0);
  }
#pragma unroll
  for (int ct = 0; ct < 4; ct++) {
    int c = w * 64 + ct * 16 + lr;
    float bc = bias[c];
#pragma unroll
    for (int r = 0; r < 4; r++) {
      int m = m0 + lg * 4 + r;
      out[(size_t)m * 256 + c] = acc[ct][r] + bc;
    }
  }
}

extern "C" void kernel_launch(void* const* d_in, const int* in_sizes, int n_in,
                              void* d_out, int out_size, void* d_ws, size_t ws_size,
                              hipStream_t stream) {
  const float* t2 = (const float*)d_in[0];
  const float* t1 = (const float*)d_in[1];
  const float* Wq = (const float*)d_in[2];
  const float* Wkv = (const float*)d_in[3];
  const float* Wp = (const float*)d_in[4];
  const float* bproj = (const float*)d_in[5];
  const float* gamma = (const float*)d_in[6];
  float* out = (float*)d_out;
  char* ws = (char*)d_ws;

  const size_t MB = 1024ull * 1024ull;
  short* Qb = (short*)(ws + 0);
  short* Kb = (short*)(ws + 4 * MB);
  float* partials = (float*)(ws + 4 * MB);  // aliases Kb (dead after flash)
  short* Vt = (short*)(ws + 8 * MB);
  short* AOb = (short*)(ws + 8 * MB);       // aliases Vt (dead after flash)
  short* Xf = (short*)(ws + 12 * MB);
  short* O0 = (short*)(ws + 16 * MB);
  short* O1 = (short*)(ws + 20 * MB);
  short* Wqt = (short*)(ws + 24 * MB);
  short* Wkvt = (short*)(ws + 24 * MB + 128 * 1024);
  short* Wpt = (short*)(ws + 24 * MB + 384 * 1024);
  float* attnc = (float*)(ws + 24 * MB + 512 * 1024);
  float* ML = (float*)(ws + 24 * MB + 576 * 1024);  // 1 MB
  short* O2 = (short*)(ws + 26 * MB);
  short* O3 = (short*)(ws + 30 * MB);

  bool big = ws_size >= 34 * MB;

  wconv<<<1024, 256, 0, stream>>>(Wq, Wkv, Wp, Wqt, Wkvt, Wpt);
  gemm_qkv3<<<dim3(256, 3), 256, 0, stream>>>(t2, t1, Wqt, Wkvt, Qb, Kb, Vt);
  if (big) {
    flash_attn_split<4><<<dim3(32, 16), 256, 0, stream>>>(Qb, Kb, Vt, O0, O1,
                                                          O2, O3, ML);
    combine_xf<4><<<dim3(64, 4), 256, 0, stream>>>(
        O0, O1, O2, O3, ML, gamma, t2, Qb, AOb, partials, Xf);
  } else {
    flash_attn_split<2><<<dim3(16, 16), 256, 0, stream>>>(Qb, Kb, Vt, O0, O1,
                                                          O1, O1, ML);
    combine_xf<2><<<dim3(64, 4), 256, 0, stream>>>(
        O0, O1, O1, O1, ML, gamma, t2, Qb, AOb, partials, Xf);
  }
  energy_reduce_softmax<<<256, 64, 0, stream>>>(partials, gamma, attnc);
  assemble_x<<<dim3(32, 4), 256, 0, stream>>>(AOb, attnc, t2, Qb, gamma, Xf);
  gemm_proj<<<512, 256, 0, stream>>>(Xf, Wpt, bproj, out);
}

// Round 15
// 76.186 us; speedup vs baseline: 1.0424x; 1.0424x over previous
//
#include <hip/hip_runtime.h>
#include <hip/hip_bf16.h>

// Problem: B=4, N=2048, C=256, H=4, d=64
// Pipeline: wconv -> gemm_qkv3(y=0:q,1:k,2:v) -> flash_attn_split<NS>
//           -> combine_xf (merge + Xf fast path; gamma-gated energy) ->
//           energy_reduce_softmax -> assemble_x (gamma!=0 only) -> gemm_proj
// flash: R12 structure (32 q/wave, K/V dbuf, 1 barrier+vmcnt/iter, fused PV)
// + XCD-aware 1-D grid: all blocks sharing one bh land on one XCD (L2 reuse).

typedef __attribute__((ext_vector_type(8))) short short8_t;
typedef __attribute__((ext_vector_type(4))) float f32x4;
typedef __attribute__((ext_vector_type(2))) unsigned u32x2;

#define NSEQ 2048

static __device__ __forceinline__ short f2bf(float f) {
  union { float f; unsigned u; } v; v.f = f;
  unsigned u = v.u;
  unsigned r = (u + 0x7FFFu + ((u >> 16) & 1u)) >> 16;
  return (short)r;
}
static __device__ __forceinline__ float bf2f(short s) {
  union { unsigned u; float f; } v;
  v.u = ((unsigned)(unsigned short)s) << 16;
  return v.f;
}
static __device__ __forceinline__ unsigned bcu(float f) {
  return __builtin_bit_cast(unsigned, f);
}
// pack two f32 into u32 of 2 bf16 (truncation) via v_perm_b32
static __device__ __forceinline__ unsigned pkbf(float lo, float hi) {
  return __builtin_amdgcn_perm(bcu(hi), bcu(lo), 0x07060302u);
}
// hardware RNE f32->bf16
static __device__ __forceinline__ short f2bf_hw(float f) {
  __hip_bfloat16 h = __float2bfloat16(f);
  return __builtin_bit_cast(short, h);
}
static __device__ __forceinline__ unsigned pk2bf_hw(float a, float b) {
  return ((unsigned)(unsigned short)__builtin_bit_cast(short, __float2bfloat16(b)) << 16) |
         (unsigned short)__builtin_bit_cast(short, __float2bfloat16(a));
}
static __device__ __forceinline__ f32x4 vmax4(f32x4 a, f32x4 b) {
  f32x4 r;
  r[0] = fmaxf(a[0], b[0]); r[1] = fmaxf(a[1], b[1]);
  r[2] = fmaxf(a[2], b[2]); r[3] = fmaxf(a[3], b[3]);
  return r;
}

// async global->LDS, 16B per lane; lds base must be wave-uniform.
static __device__ __forceinline__ void gload_lds16(const short* src, short* ldst) {
  __builtin_amdgcn_global_load_lds(
      (const __attribute__((address_space(1))) unsigned*)src,
      (__attribute__((address_space(3))) unsigned*)ldst, 16, 0, 0);
}

// ---------------------------------------------------------------- weights
__global__ __launch_bounds__(256) void wconv(
    const float* __restrict__ Wq, const float* __restrict__ Wkv,
    const float* __restrict__ Wp, short* __restrict__ Wqt,
    short* __restrict__ Wkvt, short* __restrict__ Wpt) {
  int tid = blockIdx.x * 256 + threadIdx.x;
  if (tid < 65536) {
    int n = tid >> 8, k = tid & 255;
    Wqt[tid] = f2bf(Wq[k * 256 + n]);
  } else if (tid < 196608) {
    int i = tid - 65536;
    int n = i >> 8, k = i & 255;
    Wkvt[i] = f2bf(Wkv[k * 512 + n]);
  } else {
    int i = tid - 196608;
    int n = i >> 8, k = i & 255;
    Wpt[i] = f2bf(Wp[k * 256 + n]);
  }
}

// --------------- QKV projection: LDS-staged A, 32 rows/block, 1 GEMM per block
__global__ __launch_bounds__(256) void gemm_qkv3(
    const float* __restrict__ t2, const float* __restrict__ t1,
    const short* __restrict__ Wqt, const short* __restrict__ Wkvt,
    short* __restrict__ Qb, short* __restrict__ Kb, short* __restrict__ Vtb) {
  __shared__ __align__(16) short ldsA[32 * 256];  // 16 KB, chunk-swizzled
  int tid = threadIdx.x;
  int m0 = blockIdx.x * 32;
  int y = blockIdx.y;
  const float* A = (y == 0) ? t2 : t1;

  const float* ap = A + (size_t)m0 * 256;
#pragma unroll
  for (int i = 0; i < 8; i++) {
    int idx = i * 256 + tid;
    int row = idx >> 6, c4 = idx & 63;
    f32x4 v = *(const f32x4*)(ap + (size_t)idx * 4);
    int ch8 = c4 >> 1, half = c4 & 1;
    int swz = ch8 ^ (row & 7);
    unsigned* dst = (unsigned*)&ldsA[row * 256 + swz * 8 + half * 4];
    dst[0] = pk2bf_hw(v[0], v[1]);
    dst[1] = pk2bf_hw(v[2], v[3]);
  }
  __syncthreads();

  int w = tid >> 6, l = tid & 63, lr = l & 15, lg = l >> 4;
  short8_t af[2][8];
#pragma unroll
  for (int mt = 0; mt < 2; mt++)
#pragma unroll
    for (int ks = 0; ks < 8; ks++)
      af[mt][ks] = *(const short8_t*)&ldsA[(mt * 16 + lr) * 256 +
                                           (((ks * 4 + lg) ^ (lr & 7)) * 8)];

  const short* Bt = (y == 0) ? Wqt : (y == 1 ? Wkvt : Wkvt + 65536);
  f32x4 acc[2][4] = {};
#pragma unroll
  for (int ct = 0; ct < 4; ct++) {
    const short* br = Bt + (size_t)(w * 64 + ct * 16 + lr) * 256 + lg * 8;
    short8_t bfr[8];
#pragma unroll
    for (int ks = 0; ks < 8; ks++) bfr[ks] = *(const short8_t*)(br + ks * 32);
    if (y < 2) {
#pragma unroll
      for (int ks = 0; ks < 8; ks++) {
        acc[0][ct] = __builtin_amdgcn_mfma_f32_16x16x32_bf16(af[0][ks], bfr[ks], acc[0][ct], 0, 0, 0);
        acc[1][ct] = __builtin_amdgcn_mfma_f32_16x16x32_bf16(af[1][ks], bfr[ks], acc[1][ct], 0, 0, 0);
      }
    } else {  // swapped operands for transposed V output
#pragma unroll
      for (int ks = 0; ks < 8; ks++) {
        acc[0][ct] = __builtin_amdgcn_mfma_f32_16x16x32_bf16(bfr[ks], af[0][ks], acc[0][ct], 0, 0, 0);
        acc[1][ct] = __builtin_amdgcn_mfma_f32_16x16x32_bf16(bfr[ks], af[1][ks], acc[1][ct], 0, 0, 0);
      }
    }
  }
  if (y < 2) {
    short* Ob = (y == 0) ? Qb : Kb;
#pragma unroll
    for (int ct = 0; ct < 4; ct++) {
      int c = w * 64 + ct * 16 + lr;
      int h = c >> 6, dd = c & 63;
#pragma unroll
      for (int mt = 0; mt < 2; mt++)
#pragma unroll
        for (int r = 0; r < 4; r++) {
          int m = m0 + mt * 16 + lg * 4 + r;
          int bb = m >> 11, n = m & 2047;
          Ob[(size_t)(((bb << 2) + h) * NSEQ + n) * 64 + dd] =
              f2bf_hw(acc[mt][ct][r]);
        }
    }
  } else {
#pragma unroll
    for (int ct = 0; ct < 4; ct++) {
      int c = w * 64 + ct * 16 + lg * 4;
#pragma unroll
      for (int mt = 0; mt < 2; mt++) {
        int m = m0 + mt * 16 + lr;
        int bb = m >> 11, n = m & 2047;
#pragma unroll
        for (int r = 0; r < 4; r++) {
          int cc = c + r;
          int h = cc >> 6, dd = cc & 63;
          Vtb[(size_t)(((bb << 2) + h) * 64 + dd) * NSEQ + n] =
              f2bf_hw(acc[mt][ct][r]);
        }
      }
    }
  }
}

// ---------------------------------------------------------- flash attention
// R12 structure: swapped-operand, 32 q/wave, K/V double-buffered, one
// barrier+vmcnt per k-tile, V fragments read once feeding both q-tiles.
// 1-D grid with XCD-aware decode: bh = (L&7)+8*((L>>3)&1) so all blocks of a
// bh land on one XCD (round-robin dispatch assumption; perf-only heuristic).
template <int NS>
__global__ __launch_bounds__(256, 4) void flash_attn_split(
    const short* __restrict__ Qb, const short* __restrict__ Kb,
    const short* __restrict__ Vt, short* __restrict__ O0,
    short* __restrict__ O1, short* __restrict__ O2,
    short* __restrict__ O3, float* __restrict__ ML) {
  constexpr int KITER = 32 / NS;
  __shared__ __align__(16) short ldsK[2][4096];
  __shared__ __align__(16) short ldsV[2][4096];
  __shared__ __align__(16) short ldsP[4][1024];  // [w][16 q rows][64 kv], A/B reuse
  int tid = threadIdx.x;
  int w = tid >> 6, l = tid & 63, lr = l & 15, lg = l >> 4;
  int L = blockIdx.x;
  int bh = (L & 7) + 8 * ((L >> 3) & 1);
  int rem = L >> 4;  // 0 .. 8*NS-1
  int qt = rem / NS, split = rem % NS;
  int q0 = qt * 128 + w * 32;
  const short* qpA = Qb + ((size_t)bh * NSEQ + q0 + lr) * 64 + lg * 8;
  const short* qpB = qpA + 16 * 64;
  short8_t qfA0 = *(const short8_t*)qpA;
  short8_t qfA1 = *(const short8_t*)(qpA + 32);
  short8_t qfB0 = *(const short8_t*)qpB;
  short8_t qfB1 = *(const short8_t*)(qpB + 32);
  const short* kbase = Kb + (size_t)bh * NSEQ * 64;  // [n][64]
  const short* vbase = Vt + (size_t)bh * 64 * NSEQ;  // [d][2048]

  int r0 = tid >> 3, ch0 = (tid & 7) ^ (r0 & 7);
  int kb0 = split * KITER;
  const short* ksrc = kbase + (size_t)kb0 * 4096 + (size_t)r0 * 64 + ch0 * 8;
  const short* vsrc = vbase + (size_t)r0 * NSEQ + kb0 * 64 + ch0 * 8;
  short* ldKw0 = &ldsK[0][0] + w * 512;
  short* ldKw1 = &ldsK[1][0] + w * 512;
  short* ldVw0 = &ldsV[0][0] + w * 512;
  short* ldVw1 = &ldsV[1][0] + w * 512;

#define STAGE_KV(buf_, it_)                                 \
  {                                                         \
    const short* sk_ = ksrc + (size_t)(it_) * 4096;         \
    short* dk_ = (buf_) ? ldKw1 : ldKw0;                    \
    gload_lds16(sk_, dk_);                                  \
    gload_lds16(sk_ + 2048, dk_ + 2048);                    \
    const short* sv_ = vsrc + (size_t)(it_) * 64;           \
    short* dv_ = (buf_) ? ldVw1 : ldVw0;                    \
    gload_lds16(sv_, dv_);                                  \
    gload_lds16(sv_ + 32 * NSEQ, dv_ + 2048);               \
  }

  f32x4 oA[4] = {}, oB[4] = {};
  float osumA = 0.f, osumB = 0.f, m2A = -1e30f, m2B = -1e30f;
  const float C = 0.125f * 1.44269504089f;  // SCALE * log2(e)

  int sw = lr & 7;
  int rdA = (lg ^ sw) * 8;
  int rdB = ((lg + 4) ^ sw) * 8;
  short* Pw = &ldsP[w][0];
  short* wrP = Pw + lr * 64 + (lg & 1) * 4;
  int chhi = lg >> 1;
  const short* pr0 = Pw + lr * 64 + (lg ^ sw) * 8;
  const short* pr1 = Pw + lr * 64 + ((4 + lg) ^ sw) * 8;

  STAGE_KV(0, 0);
  asm volatile("s_waitcnt vmcnt(0)" ::: "memory");
  __builtin_amdgcn_s_barrier();

  for (int i = 0; i < KITER; i++) {
    int buf = i & 1;
    if (i + 1 < KITER) STAGE_KV(buf ^ 1, i + 1);
    const short* lK = buf ? &ldsK[1][0] : &ldsK[0][0];
    const short* lV = buf ? &ldsV[1][0] : &ldsV[0][0];
    // S^T = K · Q for both q-tiles
    f32x4 sA[4], sB[4];
    __builtin_amdgcn_s_setprio(1);
#pragma unroll
    for (int t = 0; t < 4; t++) {
      const short* kr = lK + (t * 16 + lr) * 64;
      short8_t kf0 = *(const short8_t*)(kr + rdA);
      short8_t kf1 = *(const short8_t*)(kr + rdB);
      f32x4 z = {0.f, 0.f, 0.f, 0.f};
      f32x4 zA = __builtin_amdgcn_mfma_f32_16x16x32_bf16(kf0, qfA0, z, 0, 0, 0);
      sA[t] = __builtin_amdgcn_mfma_f32_16x16x32_bf16(kf1, qfA1, zA, 0, 0, 0);
      f32x4 zB = __builtin_amdgcn_mfma_f32_16x16x32_bf16(kf0, qfB0, z, 0, 0, 0);
      sB[t] = __builtin_amdgcn_mfma_f32_16x16x32_bf16(kf1, qfB1, zB, 0, 0, 0);
    }
    __builtin_amdgcn_s_setprio(0);
    // ---- tile A softmax -> P slice -> hold fragments in regs
    {
      f32x4 m4 = vmax4(vmax4(sA[0], sA[1]), vmax4(sA[2], sA[3]));
      float mx = fmaxf(fmaxf(m4[0], m4[1]), fmaxf(m4[2], m4[3]));
      mx = fmaxf(mx, __shfl_xor(mx, 16));
      mx = fmaxf(mx, __shfl_xor(mx, 32));
      mx *= C;
      float mn = fmaxf(m2A, mx);
      if (__any(mn - m2A > 8.f)) {
        float a = __builtin_amdgcn_exp2f(m2A - mn);
        m2A = mn;
        osumA *= a;
#pragma unroll
        for (int dt = 0; dt < 4; dt++) oA[dt] *= a;
      }
      float ps = 0.f;
#pragma unroll
      for (int t = 0; t < 4; t++) {
        float p0 = __builtin_amdgcn_exp2f(__builtin_fmaf(sA[t][0], C, -m2A));
        float p1 = __builtin_amdgcn_exp2f(__builtin_fmaf(sA[t][1], C, -m2A));
        float p2 = __builtin_amdgcn_exp2f(__builtin_fmaf(sA[t][2], C, -m2A));
        float p3 = __builtin_amdgcn_exp2f(__builtin_fmaf(sA[t][3], C, -m2A));
        ps += (p0 + p1) + (p2 + p3);
        u32x2 u = {pkbf(p0, p1), pkbf(p2, p3)};
        *(u32x2*)(wrP + ((2 * t + chhi) ^ sw) * 8) = u;
      }
      osumA += ps;
    }
    short8_t pfA0 = *(const short8_t*)pr0;  // hold A's P fragments
    short8_t pfA1 = *(const short8_t*)pr1;
    // ---- tile B softmax -> P slice (reuse; in-wave lgkm ordering after reads)
    {
      f32x4 m4 = vmax4(vmax4(sB[0], sB[1]), vmax4(sB[2], sB[3]));
      float mx = fmaxf(fmaxf(m4[0], m4[1]), fmaxf(m4[2], m4[3]));
      mx = fmaxf(mx, __shfl_xor(mx, 16));
      mx = fmaxf(mx, __shfl_xor(mx, 32));
      mx *= C;
      float mn = fmaxf(m2B, mx);
      if (__any(mn - m2B > 8.f)) {
        float a = __builtin_amdgcn_exp2f(m2B - mn);
        m2B = mn;
        osumB *= a;
#pragma unroll
        for (int dt = 0; dt < 4; dt++) oB[dt] *= a;
      }
      float ps = 0.f;
#pragma unroll
      for (int t = 0; t < 4; t++) {
        float p0 = __builtin_amdgcn_exp2f(__builtin_fmaf(sB[t][0], C, -m2B));
        float p1 = __builtin_amdgcn_exp2f(__builtin_fmaf(sB[t][1], C, -m2B));
        float p2 = __builtin_amdgcn_exp2f(__builtin_fmaf(sB[t][2], C, -m2B));
        float p3 = __builtin_amdgcn_exp2f(__builtin_fmaf(sB[t][3], C, -m2B));
        ps += (p0 + p1) + (p2 + p3);
        u32x2 u = {pkbf(p0, p1), pkbf(p2, p3)};
        *(u32x2*)(wrP + ((2 * t + chhi) ^ sw) * 8) = u;
      }
      osumB += ps;
    }
    short8_t pfB0 = *(const short8_t*)pr0;
    short8_t pfB1 = *(const short8_t*)pr1;
    // ---- fused PV: V fragments read once, feed both q-tiles
    __builtin_amdgcn_s_setprio(1);
#pragma unroll
    for (int dt = 0; dt < 4; dt++) {
      const short* vr = lV + (dt * 16 + lr) * 64;
      short8_t vf0 = *(const short8_t*)(vr + rdA);
      short8_t vf1 = *(const short8_t*)(vr + rdB);
      oA[dt] = __builtin_amdgcn_mfma_f32_16x16x32_bf16(vf0, pfA0, oA[dt], 0, 0, 0);
      oA[dt] = __builtin_amdgcn_mfma_f32_16x16x32_bf16(vf1, pfA1, oA[dt], 0, 0, 0);
      oB[dt] = __builtin_amdgcn_mfma_f32_16x16x32_bf16(vf0, pfB0, oB[dt], 0, 0, 0);
      oB[dt] = __builtin_amdgcn_mfma_f32_16x16x32_bf16(vf1, pfB1, oB[dt], 0, 0, 0);
    }
    __builtin_amdgcn_s_setprio(0);
    if (i + 1 < KITER) {
      asm volatile("s_waitcnt vmcnt(0)" ::: "memory");  // next K/V landed
      __builtin_amdgcn_s_barrier();
    }
  }
#undef STAGE_KV
  osumA += __shfl_xor(osumA, 16);
  osumA += __shfl_xor(osumA, 32);
  osumB += __shfl_xor(osumB, 16);
  osumB += __shfl_xor(osumB, 32);
  float invA = __builtin_amdgcn_rcpf(osumA);
  float invB = __builtin_amdgcn_rcpf(osumB);
  short* op = (split == 0) ? O0 : (split == 1) ? O1 : (split == 2) ? O2 : O3;
#pragma unroll
  for (int dt = 0; dt < 4; dt++)
#pragma unroll
    for (int r = 0; r < 4; r++) {
      size_t drow = ((size_t)bh * 64 + dt * 16 + lg * 4 + r) * NSEQ;
      op[drow + q0 + lr] = f2bf_hw(oA[dt][r] * invA);
      op[drow + q0 + 16 + lr] = f2bf_hw(oB[dt][r] * invB);
    }
  if (lg == 0) {
    float2 vA = {m2A, osumA};
    float2 vB = {m2B, osumB};
    *(float2*)&ML[((size_t)bh * NSEQ + q0 + lr) * 8 + split * 2] = vA;
    *(float2*)&ML[((size_t)bh * NSEQ + q0 + 16 + lr) * 8 + split * 2] = vB;
  }
}

// -------- merge splits; gamma==0: write Xf directly (t2 + x + q residuals);
//          gamma!=0: write AOb + energy partials via MFMA.
template <int NS>
__global__ __launch_bounds__(256) void combine_xf(
    const short* __restrict__ O0, const short* __restrict__ O1,
    const short* __restrict__ O2, const short* __restrict__ O3,
    const float* __restrict__ ML, const float* __restrict__ gamma,
    const float* __restrict__ t2, const short* __restrict__ Qb,
    short* __restrict__ AOb, float* __restrict__ partials,
    short* __restrict__ Xf) {
  __shared__ __align__(16) short tileT[64][128];  // [dd][m], chunk-swizzled
  __shared__ f32x4 wcol[128];                     // per-column merge coeffs
  int tid = threadIdx.x;
  int b = blockIdx.y, kc = blockIdx.x;
  int h = kc >> 4, n0 = (kc & 15) * 128;
  int bh = (b << 2) + h;
  float g = gamma[0];
  if (tid < 128) {
    const float* ml = ML + ((size_t)bh * NSEQ + n0 + tid) * 8;
    f32x4 a = *(const f32x4*)ml;  // m0,s0,m1,s1
    f32x4 c;
    if (NS == 2) {
      float M = fmaxf(a[0], a[2]);
      float w0 = a[1] * __builtin_amdgcn_exp2f(a[0] - M);
      float w1 = a[3] * __builtin_amdgcn_exp2f(a[2] - M);
      float iv = __builtin_amdgcn_rcpf(w0 + w1);
      c[0] = w0 * iv; c[1] = w1 * iv; c[2] = 0.f; c[3] = 0.f;
    } else {
      f32x4 bq = *(const f32x4*)(ml + 4);  // m2,s2,m3,s3
      float M = fmaxf(fmaxf(a[0], a[2]), fmaxf(bq[0], bq[2]));
      float w0 = a[1] * __builtin_amdgcn_exp2f(a[0] - M);
      float w1 = a[3] * __builtin_amdgcn_exp2f(a[2] - M);
      float w2 = bq[1] * __builtin_amdgcn_exp2f(bq[0] - M);
      float w3 = bq[3] * __builtin_amdgcn_exp2f(bq[2] - M);
      float iv = __builtin_amdgcn_rcpf(w0 + w1 + w2 + w3);
      c[0] = w0 * iv; c[1] = w1 * iv; c[2] = w2 * iv; c[3] = w3 * iv;
    }
    wcol[tid] = c;
  }
  __syncthreads();
  {
    int chunk = tid & 15;   // 16B chunk within 128-col row (8 bf16)
    int rw = tid >> 4;      // 0..15
#pragma unroll
    for (int i = 0; i < 4; i++) {
      int row = rw + 16 * i;
      size_t gbase = ((size_t)bh * 64 + row) * NSEQ + n0 + chunk * 8;
      short8_t v0 = *(const short8_t*)(O0 + gbase);
      short8_t v1 = *(const short8_t*)(O1 + gbase);
      short8_t v2{}, v3{};
      if (NS == 4) {
        v2 = *(const short8_t*)(O2 + gbase);
        v3 = *(const short8_t*)(O3 + gbase);
      }
      short8_t comb;
#pragma unroll
      for (int j = 0; j < 8; j++) {
        f32x4 c = wcol[chunk * 8 + j];
        float val = bf2f(v0[j]) * c[0] + bf2f(v1[j]) * c[1];
        if (NS == 4) val += bf2f(v2[j]) * c[2] + bf2f(v3[j]) * c[3];
        comb[j] = f2bf_hw(val);
      }
      if (g != 0.f) *(short8_t*)(AOb + gbase) = comb;
      *(short8_t*)&tileT[row][(chunk ^ (row & 15)) * 8] = comb;
    }
  }
  __syncthreads();
  if (g == 0.f) {
    int nc = tid >> 1, half = tid & 1;
    int n = n0 + nc;
    int cidx = nc >> 3, jj = nc & 7;
    const float* t2p = t2 + ((size_t)b * NSEQ + n) * 256 + h * 64 + half * 32;
    const short* qp = Qb + ((size_t)bh * NSEQ + n) * 64 + half * 32;
    short* xfp = Xf + ((size_t)b * NSEQ + n) * 256 + h * 64 + half * 32;
#pragma unroll
    for (int i = 0; i < 4; i++) {
      int ddb = half * 32 + i * 8;
      f32x4 ta = *(const f32x4*)(t2p + i * 8);
      f32x4 tb = *(const f32x4*)(t2p + i * 8 + 4);
      short8_t q8 = *(const short8_t*)(qp + i * 8);
      short8_t r;
#pragma unroll
      for (int j = 0; j < 8; j++) {
        int dd = ddb + j;
        short xv = tileT[dd][((cidx ^ (dd & 15)) * 8) + jj];
        float t = (j < 4) ? ta[j] : tb[j - 4];
        r[j] = f2bf_hw(t + bf2f(xv) + bf2f(q8[j]));
      }
      *(short8_t*)(xfp + i * 8) = r;
    }
    return;
  }
  int w = tid >> 6, lr = tid & 15, lg = (tid & 63) >> 4;
  f32x4 acc[4] = {};
#pragma unroll
  for (int ks = 0; ks < 4; ks++) {
    short8_t af = *(const short8_t*)&tileT[w * 16 + lr][((ks * 4 + lg) ^ lr) * 8];
#pragma unroll
    for (int e = 0; e < 4; e++) {
      short8_t bf = *(const short8_t*)&tileT[e * 16 + lr][((ks * 4 + lg) ^ lr) * 8];
      acc[e] = __builtin_amdgcn_mfma_f32_16x16x32_bf16(af, bf, acc[e], 0, 0, 0);
    }
  }
  float* dst = partials + ((size_t)b * 64 + kc) * 4096;
#pragma unroll
  for (int e = 0; e < 4; e++)
#pragma unroll
    for (int r = 0; r < 4; r++)
      dst[(w * 16 + lg * 4 + r) * 64 + e * 16 + lr] = acc[e][r];
}

// -------------------------------- reduce partials over kc + channel softmax
__global__ __launch_bounds__(64) void energy_reduce_softmax(
    const float* __restrict__ partials, const float* __restrict__ gamma,
    float* __restrict__ attnc) {
  if (gamma[0] == 0.f) return;  // attnc unread when gamma == 0
  int row = blockIdx.x;  // b*64 + d
  int b = row >> 6, d = row & 63;
  int e = threadIdx.x;
  const float* src = partials + (size_t)b * 64 * 4096 + d * 64 + e;
  float s = 0.f;
#pragma unroll 8
  for (int kc = 0; kc < 64; kc++) s += src[(size_t)kc * 4096];
  float mx = s;
#pragma unroll
  for (int x = 1; x < 64; x <<= 1) mx = fmaxf(mx, __shfl_xor(mx, x, 64));
  float ev = __expf(s - mx);
  float sum = ev;
#pragma unroll
  for (int x = 1; x < 64; x <<= 1) sum += __shfl_xor(sum, x, 64);
  attnc[row * 64 + e] = ev / sum;
}

// ----------------------- lam apply + residuals (gamma != 0 slow path only)
__global__ __launch_bounds__(256) void assemble_x(
    const short* __restrict__ AOb, const float* __restrict__ attnc,
    const float* __restrict__ t2, const short* __restrict__ Qb,
    const float* __restrict__ gamma, short* __restrict__ Xf) {
  float g = gamma[0];
  if (g == 0.f) return;  // Xf already written by combine_xf fast path
  __shared__ f32x4 At4[1024];
  int b = blockIdx.y, tid = threadIdx.x;
  const f32x4* ac = (const f32x4*)(attnc + (size_t)b * 4096);
#pragma unroll
  for (int i = 0; i < 4; i++) At4[i * 256 + tid] = ac[i * 256 + tid];
  __syncthreads();
  int rowb = blockIdx.x * 256 + tid;
  int h = rowb >> 11, n = rowb & 2047;
  const short* xop = AOb + ((size_t)((b << 2) + h) * 64) * NSEQ + n;
  f32x4 xv[16];
#pragma unroll
  for (int i = 0; i < 16; i++) {
    f32x4 t;
    t[0] = bf2f(xop[(size_t)(4 * i + 0) * NSEQ]);
    t[1] = bf2f(xop[(size_t)(4 * i + 1) * NSEQ]);
    t[2] = bf2f(xop[(size_t)(4 * i + 2) * NSEQ]);
    t[3] = bf2f(xop[(size_t)(4 * i + 3) * NSEQ]);
    xv[i] = t;
  }
  const short* qp = Qb + ((size_t)b * 8192 + rowb) * 64;
  const float* t2p = t2 + ((size_t)b * 2048 + n) * 256 + h * 64;
  short* xfp = Xf + ((size_t)b * 2048 + n) * 256 + h * 64;
#pragma unroll
  for (int dd = 0; dd < 64; dd++) {
    f32x4 a = {0.f, 0.f, 0.f, 0.f};
#pragma unroll
    for (int j = 0; j < 16; j++) a += At4[dd * 16 + j] * xv[j];
    float o = (a[0] + a[1] + a[2] + a[3]) * g;
    float val = t2p[dd] + o + xv[dd >> 2][dd & 3] + bf2f(qp[dd]);
    xfp[dd] = f2bf_hw(val);
  }
}

// ------------------- final projection + bias (LDS-staged A, 16 rows/block)
__global__ __launch_bounds__(256) void gemm_proj(
    const short* __restrict__ Xf, const short* __restrict__ Wpt,
    const float* __restrict__ bias, float* __restrict__ out) {
  __shared__ __align__(16) short ldsA[16 * 256];  // 8 KB, chunk-swizzled
  int tid = threadIdx.x;
  int w = tid >> 6, l = tid & 63, lr = l & 15, lg = l >> 4;
  int m0 = blockIdx.x * 16;
#pragma unroll
  for (int i = 0; i < 2; i++) {
    int c = w * 128 + i * 64 + l;  // LDS chunk id (16B units)
    int row = c >> 5, ch = c & 31;
    int chs = (ch & 24) | ((ch & 7) ^ (row & 7));
    gload_lds16(Xf + (size_t)(m0 + row) * 256 + chs * 8,
                &ldsA[(w * 128 + i * 64) * 8]);
  }
  asm volatile("s_waitcnt vmcnt(0)" ::: "memory");
  __syncthreads();
  short8_t af[8];
#pragma unroll
  for (int ks = 0; ks < 8; ks++)
    af[ks] = *(const short8_t*)&ldsA[lr * 256 + (((ks * 4 + lg) ^ (lr & 7)) * 8)];
  f32x4 acc[4] = {};
#pragma unroll
  for (int ct = 0; ct < 4; ct++) {
    const short* br = Wpt + (size_t)(w * 64 + ct * 16 + lr) * 256 + lg * 8;
    short8_t bfr[8];
#pragma unroll
    for (int ks = 0; ks < 8; ks++) bfr[ks] = *(const short8_t*)(br + ks * 32);
#pragma unroll
    for (int ks = 0; ks < 8; ks++)
      acc[ct] = __builtin_amdgcn_mfma_f32_16x16x32_bf16(af[ks], bfr[ks], acc[ct], 0, 0, 0);
  }
#pragma unroll
  for (int ct = 0; ct < 4; ct++) {
    int c = w * 64 + ct * 16 + lr;
    float bc = bias[c];
#pragma unroll
    for (int r = 0; r < 4; r++) {
      int m = m0 + lg * 4 + r;
      out[(size_t)m * 256 + c] = acc[ct][r] + bc;
    }
  }
}

extern "C" void kernel_launch(void* const* d_in, const int* in_sizes, int n_in,
                              void* d_out, int out_size, void* d_ws, size_t ws_size,
                              hipStream_t stream) {
  const float* t2 = (const float*)d_in[0];
  const float* t1 = (const float*)d_in[1];
  const float* Wq = (const float*)d_in[2];
  const float* Wkv = (const float*)d_in[3];
  const float* Wp = (const float*)d_in[4];
  const float* bproj = (const float*)d_in[5];
  const float* gamma = (const float*)d_in[6];
  float* out = (float*)d_out;
  char* ws = (char*)d_ws;

  const size_t MB = 1024ull * 1024ull;
  short* Qb = (short*)(ws + 0);
  short* Kb = (short*)(ws + 4 * MB);
  float* partials = (float*)(ws + 4 * MB);  // aliases Kb (dead after flash)
  short* Vt = (short*)(ws + 8 * MB);
  short* AOb = (short*)(ws + 8 * MB);       // aliases Vt (dead after flash)
  short* Xf = (short*)(ws + 12 * MB);
  short* O0 = (short*)(ws + 16 * MB);
  short* O1 = (short*)(ws + 20 * MB);
  short* Wqt = (short*)(ws + 24 * MB);
  short* Wkvt = (short*)(ws + 24 * MB + 128 * 1024);
  short* Wpt = (short*)(ws + 24 * MB + 384 * 1024);
  float* attnc = (float*)(ws + 24 * MB + 512 * 1024);
  float* ML = (float*)(ws + 24 * MB + 576 * 1024);  // 1 MB
  short* O2 = (short*)(ws + 26 * MB);
  short* O3 = (short*)(ws + 30 * MB);

  bool big = ws_size >= 34 * MB;

  wconv<<<1024, 256, 0, stream>>>(Wq, Wkv, Wp, Wqt, Wkvt, Wpt);
  gemm_qkv3<<<dim3(256, 3), 256, 0, stream>>>(t2, t1, Wqt, Wkvt, Qb, Kb, Vt);
  if (big) {
    flash_attn_split<4><<<1024, 256, 0, stream>>>(Qb, Kb, Vt, O0, O1, O2, O3,
                                                  ML);
    combine_xf<4><<<dim3(64, 4), 256, 0, stream>>>(
        O0, O1, O2, O3, ML, gamma, t2, Qb, AOb, partials, Xf);
  } else {
    flash_attn_split<2><<<512, 256, 0, stream>>>(Qb, Kb, Vt, O0, O1, O1, O1,
                                                 ML);
    combine_xf<2><<<dim3(64, 4), 256, 0, stream>>>(
        O0, O1, O1, O1, ML, gamma, t2, Qb, AOb, partials, Xf);
  }
  energy_reduce_softmax<<<256, 64, 0, stream>>>(partials, gamma, attnc);
  assemble_x<<<dim3(32, 4), 256, 0, stream>>>(AOb, attnc, t2, Qb, gamma, Xf);
  gemm_proj<<<512, 256, 0, stream>>>(Xf, Wpt, bproj, out);
}

// Round 16
// 74.349 us; speedup vs baseline: 1.0681x; 1.0247x over previous
//
#include <hip/hip_runtime.h>
#include <hip/hip_bf16.h>

// Problem: B=4, N=2048, C=256, H=4, d=64
// Pipeline: wconv -> gemm_qkv3(y=0:q,1:k,2:v) -> flash_attn_split<NS>
//           -> combine_xf (merge + Xf fast path; gamma-gated energy) ->
//           energy_reduce_softmax -> assemble_x (gamma!=0 only) -> gemm_proj
// flash: R14 config (32 q/wave, K/V dbuf, 1 barrier+vmcnt/iter, fused PV,
// XCD-aware 1-D grid). combine_xf: 64x64 tiles, 512 blocks (2/CU).

typedef __attribute__((ext_vector_type(8))) short short8_t;
typedef __attribute__((ext_vector_type(4))) float f32x4;
typedef __attribute__((ext_vector_type(2))) unsigned u32x2;

#define NSEQ 2048

static __device__ __forceinline__ short f2bf(float f) {
  union { float f; unsigned u; } v; v.f = f;
  unsigned u = v.u;
  unsigned r = (u + 0x7FFFu + ((u >> 16) & 1u)) >> 16;
  return (short)r;
}
static __device__ __forceinline__ float bf2f(short s) {
  union { unsigned u; float f; } v;
  v.u = ((unsigned)(unsigned short)s) << 16;
  return v.f;
}
static __device__ __forceinline__ unsigned bcu(float f) {
  return __builtin_bit_cast(unsigned, f);
}
// pack two f32 into u32 of 2 bf16 (truncation) via v_perm_b32
static __device__ __forceinline__ unsigned pkbf(float lo, float hi) {
  return __builtin_amdgcn_perm(bcu(hi), bcu(lo), 0x07060302u);
}
// hardware RNE f32->bf16
static __device__ __forceinline__ short f2bf_hw(float f) {
  __hip_bfloat16 h = __float2bfloat16(f);
  return __builtin_bit_cast(short, h);
}
static __device__ __forceinline__ unsigned pk2bf_hw(float a, float b) {
  return ((unsigned)(unsigned short)__builtin_bit_cast(short, __float2bfloat16(b)) << 16) |
         (unsigned short)__builtin_bit_cast(short, __float2bfloat16(a));
}
static __device__ __forceinline__ f32x4 vmax4(f32x4 a, f32x4 b) {
  f32x4 r;
  r[0] = fmaxf(a[0], b[0]); r[1] = fmaxf(a[1], b[1]);
  r[2] = fmaxf(a[2], b[2]); r[3] = fmaxf(a[3], b[3]);
  return r;
}

// async global->LDS, 16B per lane; lds base must be wave-uniform.
static __device__ __forceinline__ void gload_lds16(const short* src, short* ldst) {
  __builtin_amdgcn_global_load_lds(
      (const __attribute__((address_space(1))) unsigned*)src,
      (__attribute__((address_space(3))) unsigned*)ldst, 16, 0, 0);
}

// ---------------------------------------------------------------- weights
__global__ __launch_bounds__(256) void wconv(
    const float* __restrict__ Wq, const float* __restrict__ Wkv,
    const float* __restrict__ Wp, short* __restrict__ Wqt,
    short* __restrict__ Wkvt, short* __restrict__ Wpt) {
  int tid = blockIdx.x * 256 + threadIdx.x;
  if (tid < 65536) {
    int n = tid >> 8, k = tid & 255;
    Wqt[tid] = f2bf(Wq[k * 256 + n]);
  } else if (tid < 196608) {
    int i = tid - 65536;
    int n = i >> 8, k = i & 255;
    Wkvt[i] = f2bf(Wkv[k * 512 + n]);
  } else {
    int i = tid - 196608;
    int n = i >> 8, k = i & 255;
    Wpt[i] = f2bf(Wp[k * 256 + n]);
  }
}

// --------------- QKV projection: LDS-staged A, 32 rows/block, 1 GEMM per block
__global__ __launch_bounds__(256) void gemm_qkv3(
    const float* __restrict__ t2, const float* __restrict__ t1,
    const short* __restrict__ Wqt, const short* __restrict__ Wkvt,
    short* __restrict__ Qb, short* __restrict__ Kb, short* __restrict__ Vtb) {
  __shared__ __align__(16) short ldsA[32 * 256];  // 16 KB, chunk-swizzled
  int tid = threadIdx.x;
  int m0 = blockIdx.x * 32;
  int y = blockIdx.y;
  const float* A = (y == 0) ? t2 : t1;

  const float* ap = A + (size_t)m0 * 256;
#pragma unroll
  for (int i = 0; i < 8; i++) {
    int idx = i * 256 + tid;
    int row = idx >> 6, c4 = idx & 63;
    f32x4 v = *(const f32x4*)(ap + (size_t)idx * 4);
    int ch8 = c4 >> 1, half = c4 & 1;
    int swz = ch8 ^ (row & 7);
    unsigned* dst = (unsigned*)&ldsA[row * 256 + swz * 8 + half * 4];
    dst[0] = pk2bf_hw(v[0], v[1]);
    dst[1] = pk2bf_hw(v[2], v[3]);
  }
  __syncthreads();

  int w = tid >> 6, l = tid & 63, lr = l & 15, lg = l >> 4;
  short8_t af[2][8];
#pragma unroll
  for (int mt = 0; mt < 2; mt++)
#pragma unroll
    for (int ks = 0; ks < 8; ks++)
      af[mt][ks] = *(const short8_t*)&ldsA[(mt * 16 + lr) * 256 +
                                           (((ks * 4 + lg) ^ (lr & 7)) * 8)];

  const short* Bt = (y == 0) ? Wqt : (y == 1 ? Wkvt : Wkvt + 65536);
  f32x4 acc[2][4] = {};
#pragma unroll
  for (int ct = 0; ct < 4; ct++) {
    const short* br = Bt + (size_t)(w * 64 + ct * 16 + lr) * 256 + lg * 8;
    short8_t bfr[8];
#pragma unroll
    for (int ks = 0; ks < 8; ks++) bfr[ks] = *(const short8_t*)(br + ks * 32);
    if (y < 2) {
#pragma unroll
      for (int ks = 0; ks < 8; ks++) {
        acc[0][ct] = __builtin_amdgcn_mfma_f32_16x16x32_bf16(af[0][ks], bfr[ks], acc[0][ct], 0, 0, 0);
        acc[1][ct] = __builtin_amdgcn_mfma_f32_16x16x32_bf16(af[1][ks], bfr[ks], acc[1][ct], 0, 0, 0);
      }
    } else {  // swapped operands for transposed V output
#pragma unroll
      for (int ks = 0; ks < 8; ks++) {
        acc[0][ct] = __builtin_amdgcn_mfma_f32_16x16x32_bf16(bfr[ks], af[0][ks], acc[0][ct], 0, 0, 0);
        acc[1][ct] = __builtin_amdgcn_mfma_f32_16x16x32_bf16(bfr[ks], af[1][ks], acc[1][ct], 0, 0, 0);
      }
    }
  }
  if (y < 2) {
    short* Ob = (y == 0) ? Qb : Kb;
#pragma unroll
    for (int ct = 0; ct < 4; ct++) {
      int c = w * 64 + ct * 16 + lr;
      int h = c >> 6, dd = c & 63;
#pragma unroll
      for (int mt = 0; mt < 2; mt++)
#pragma unroll
        for (int r = 0; r < 4; r++) {
          int m = m0 + mt * 16 + lg * 4 + r;
          int bb = m >> 11, n = m & 2047;
          Ob[(size_t)(((bb << 2) + h) * NSEQ + n) * 64 + dd] =
              f2bf_hw(acc[mt][ct][r]);
        }
    }
  } else {
#pragma unroll
    for (int ct = 0; ct < 4; ct++) {
      int c = w * 64 + ct * 16 + lg * 4;
#pragma unroll
      for (int mt = 0; mt < 2; mt++) {
        int m = m0 + mt * 16 + lr;
        int bb = m >> 11, n = m & 2047;
#pragma unroll
        for (int r = 0; r < 4; r++) {
          int cc = c + r;
          int h = cc >> 6, dd = cc & 63;
          Vtb[(size_t)(((bb << 2) + h) * 64 + dd) * NSEQ + n] =
              f2bf_hw(acc[mt][ct][r]);
        }
      }
    }
  }
}

// ---------------------------------------------------------- flash attention
// R14 config: swapped-operand, 32 q/wave, K/V double-buffered, one
// barrier+vmcnt per k-tile, V fragments read once feeding both q-tiles,
// XCD-aware 1-D grid: bh = (L&7)+8*((L>>3)&1).
template <int NS>
__global__ __launch_bounds__(256, 4) void flash_attn_split(
    const short* __restrict__ Qb, const short* __restrict__ Kb,
    const short* __restrict__ Vt, short* __restrict__ O0,
    short* __restrict__ O1, short* __restrict__ O2,
    short* __restrict__ O3, float* __restrict__ ML) {
  constexpr int KITER = 32 / NS;
  __shared__ __align__(16) short ldsK[2][4096];
  __shared__ __align__(16) short ldsV[2][4096];
  __shared__ __align__(16) short ldsP[4][1024];  // [w][16 q rows][64 kv], A/B reuse
  int tid = threadIdx.x;
  int w = tid >> 6, l = tid & 63, lr = l & 15, lg = l >> 4;
  int L = blockIdx.x;
  int bh = (L & 7) + 8 * ((L >> 3) & 1);
  int rem = L >> 4;  // 0 .. 8*NS-1
  int qt = rem / NS, split = rem % NS;
  int q0 = qt * 128 + w * 32;
  const short* qpA = Qb + ((size_t)bh * NSEQ + q0 + lr) * 64 + lg * 8;
  const short* qpB = qpA + 16 * 64;
  short8_t qfA0 = *(const short8_t*)qpA;
  short8_t qfA1 = *(const short8_t*)(qpA + 32);
  short8_t qfB0 = *(const short8_t*)qpB;
  short8_t qfB1 = *(const short8_t*)(qpB + 32);
  const short* kbase = Kb + (size_t)bh * NSEQ * 64;  // [n][64]
  const short* vbase = Vt + (size_t)bh * 64 * NSEQ;  // [d][2048]

  int r0 = tid >> 3, ch0 = (tid & 7) ^ (r0 & 7);
  int kb0 = split * KITER;
  const short* ksrc = kbase + (size_t)kb0 * 4096 + (size_t)r0 * 64 + ch0 * 8;
  const short* vsrc = vbase + (size_t)r0 * NSEQ + kb0 * 64 + ch0 * 8;
  short* ldKw0 = &ldsK[0][0] + w * 512;
  short* ldKw1 = &ldsK[1][0] + w * 512;
  short* ldVw0 = &ldsV[0][0] + w * 512;
  short* ldVw1 = &ldsV[1][0] + w * 512;

#define STAGE_KV(buf_, it_)                                 \
  {                                                         \
    const short* sk_ = ksrc + (size_t)(it_) * 4096;         \
    short* dk_ = (buf_) ? ldKw1 : ldKw0;                    \
    gload_lds16(sk_, dk_);                                  \
    gload_lds16(sk_ + 2048, dk_ + 2048);                    \
    const short* sv_ = vsrc + (size_t)(it_) * 64;           \
    short* dv_ = (buf_) ? ldVw1 : ldVw0;                    \
    gload_lds16(sv_, dv_);                                  \
    gload_lds16(sv_ + 32 * NSEQ, dv_ + 2048);               \
  }

  f32x4 oA[4] = {}, oB[4] = {};
  float osumA = 0.f, osumB = 0.f, m2A = -1e30f, m2B = -1e30f;
  const float C = 0.125f * 1.44269504089f;  // SCALE * log2(e)

  int sw = lr & 7;
  int rdA = (lg ^ sw) * 8;
  int rdB = ((lg + 4) ^ sw) * 8;
  short* Pw = &ldsP[w][0];
  short* wrP = Pw + lr * 64 + (lg & 1) * 4;
  int chhi = lg >> 1;
  const short* pr0 = Pw + lr * 64 + (lg ^ sw) * 8;
  const short* pr1 = Pw + lr * 64 + ((4 + lg) ^ sw) * 8;

  STAGE_KV(0, 0);
  asm volatile("s_waitcnt vmcnt(0)" ::: "memory");
  __builtin_amdgcn_s_barrier();

  for (int i = 0; i < KITER; i++) {
    int buf = i & 1;
    if (i + 1 < KITER) STAGE_KV(buf ^ 1, i + 1);
    const short* lK = buf ? &ldsK[1][0] : &ldsK[0][0];
    const short* lV = buf ? &ldsV[1][0] : &ldsV[0][0];
    // S^T = K · Q for both q-tiles
    f32x4 sA[4], sB[4];
    __builtin_amdgcn_s_setprio(1);
#pragma unroll
    for (int t = 0; t < 4; t++) {
      const short* kr = lK + (t * 16 + lr) * 64;
      short8_t kf0 = *(const short8_t*)(kr + rdA);
      short8_t kf1 = *(const short8_t*)(kr + rdB);
      f32x4 z = {0.f, 0.f, 0.f, 0.f};
      f32x4 zA = __builtin_amdgcn_mfma_f32_16x16x32_bf16(kf0, qfA0, z, 0, 0, 0);
      sA[t] = __builtin_amdgcn_mfma_f32_16x16x32_bf16(kf1, qfA1, zA, 0, 0, 0);
      f32x4 zB = __builtin_amdgcn_mfma_f32_16x16x32_bf16(kf0, qfB0, z, 0, 0, 0);
      sB[t] = __builtin_amdgcn_mfma_f32_16x16x32_bf16(kf1, qfB1, zB, 0, 0, 0);
    }
    __builtin_amdgcn_s_setprio(0);
    // ---- tile A softmax -> P slice -> hold fragments in regs
    {
      f32x4 m4 = vmax4(vmax4(sA[0], sA[1]), vmax4(sA[2], sA[3]));
      float mx = fmaxf(fmaxf(m4[0], m4[1]), fmaxf(m4[2], m4[3]));
      mx = fmaxf(mx, __shfl_xor(mx, 16));
      mx = fmaxf(mx, __shfl_xor(mx, 32));
      mx *= C;
      float mn = fmaxf(m2A, mx);
      if (__any(mn - m2A > 8.f)) {
        float a = __builtin_amdgcn_exp2f(m2A - mn);
        m2A = mn;
        osumA *= a;
#pragma unroll
        for (int dt = 0; dt < 4; dt++) oA[dt] *= a;
      }
      float ps = 0.f;
#pragma unroll
      for (int t = 0; t < 4; t++) {
        float p0 = __builtin_amdgcn_exp2f(__builtin_fmaf(sA[t][0], C, -m2A));
        float p1 = __builtin_amdgcn_exp2f(__builtin_fmaf(sA[t][1], C, -m2A));
        float p2 = __builtin_amdgcn_exp2f(__builtin_fmaf(sA[t][2], C, -m2A));
        float p3 = __builtin_amdgcn_exp2f(__builtin_fmaf(sA[t][3], C, -m2A));
        ps += (p0 + p1) + (p2 + p3);
        u32x2 u = {pkbf(p0, p1), pkbf(p2, p3)};
        *(u32x2*)(wrP + ((2 * t + chhi) ^ sw) * 8) = u;
      }
      osumA += ps;
    }
    short8_t pfA0 = *(const short8_t*)pr0;  // hold A's P fragments
    short8_t pfA1 = *(const short8_t*)pr1;
    // ---- tile B softmax -> P slice (reuse; in-wave lgkm ordering after reads)
    {
      f32x4 m4 = vmax4(vmax4(sB[0], sB[1]), vmax4(sB[2], sB[3]));
      float mx = fmaxf(fmaxf(m4[0], m4[1]), fmaxf(m4[2], m4[3]));
      mx = fmaxf(mx, __shfl_xor(mx, 16));
      mx = fmaxf(mx, __shfl_xor(mx, 32));
      mx *= C;
      float mn = fmaxf(m2B, mx);
      if (__any(mn - m2B > 8.f)) {
        float a = __builtin_amdgcn_exp2f(m2B - mn);
        m2B = mn;
        osumB *= a;
#pragma unroll
        for (int dt = 0; dt < 4; dt++) oB[dt] *= a;
      }
      float ps = 0.f;
#pragma unroll
      for (int t = 0; t < 4; t++) {
        float p0 = __builtin_amdgcn_exp2f(__builtin_fmaf(sB[t][0], C, -m2B));
        float p1 = __builtin_amdgcn_exp2f(__builtin_fmaf(sB[t][1], C, -m2B));
        float p2 = __builtin_amdgcn_exp2f(__builtin_fmaf(sB[t][2], C, -m2B));
        float p3 = __builtin_amdgcn_exp2f(__builtin_fmaf(sB[t][3], C, -m2B));
        ps += (p0 + p1) + (p2 + p3);
        u32x2 u = {pkbf(p0, p1), pkbf(p2, p3)};
        *(u32x2*)(wrP + ((2 * t + chhi) ^ sw) * 8) = u;
      }
      osumB += ps;
    }
    short8_t pfB0 = *(const short8_t*)pr0;
    short8_t pfB1 = *(const short8_t*)pr1;
    // ---- fused PV: V fragments read once, feed both q-tiles
    __builtin_amdgcn_s_setprio(1);
#pragma unroll
    for (int dt = 0; dt < 4; dt++) {
      const short* vr = lV + (dt * 16 + lr) * 64;
      short8_t vf0 = *(const short8_t*)(vr + rdA);
      short8_t vf1 = *(const short8_t*)(vr + rdB);
      oA[dt] = __builtin_amdgcn_mfma_f32_16x16x32_bf16(vf0, pfA0, oA[dt], 0, 0, 0);
      oA[dt] = __builtin_amdgcn_mfma_f32_16x16x32_bf16(vf1, pfA1, oA[dt], 0, 0, 0);
      oB[dt] = __builtin_amdgcn_mfma_f32_16x16x32_bf16(vf0, pfB0, oB[dt], 0, 0, 0);
      oB[dt] = __builtin_amdgcn_mfma_f32_16x16x32_bf16(vf1, pfB1, oB[dt], 0, 0, 0);
    }
    __builtin_amdgcn_s_setprio(0);
    if (i + 1 < KITER) {
      asm volatile("s_waitcnt vmcnt(0)" ::: "memory");  // next K/V landed
      __builtin_amdgcn_s_barrier();
    }
  }
#undef STAGE_KV
  osumA += __shfl_xor(osumA, 16);
  osumA += __shfl_xor(osumA, 32);
  osumB += __shfl_xor(osumB, 16);
  osumB += __shfl_xor(osumB, 32);
  float invA = __builtin_amdgcn_rcpf(osumA);
  float invB = __builtin_amdgcn_rcpf(osumB);
  short* op = (split == 0) ? O0 : (split == 1) ? O1 : (split == 2) ? O2 : O3;
#pragma unroll
  for (int dt = 0; dt < 4; dt++)
#pragma unroll
    for (int r = 0; r < 4; r++) {
      size_t drow = ((size_t)bh * 64 + dt * 16 + lg * 4 + r) * NSEQ;
      op[drow + q0 + lr] = f2bf_hw(oA[dt][r] * invA);
      op[drow + q0 + 16 + lr] = f2bf_hw(oB[dt][r] * invB);
    }
  if (lg == 0) {
    float2 vA = {m2A, osumA};
    float2 vB = {m2B, osumB};
    *(float2*)&ML[((size_t)bh * NSEQ + q0 + lr) * 8 + split * 2] = vA;
    *(float2*)&ML[((size_t)bh * NSEQ + q0 + 16 + lr) * 8 + split * 2] = vB;
  }
}

// -------- merge splits (64 d x 64 n tiles, 512 blocks); gamma==0: write Xf
//          directly; gamma!=0: write AOb + energy partials via MFMA.
// grid (128 = h*32+nblk, 4 = b).
template <int NS>
__global__ __launch_bounds__(256) void combine_xf(
    const short* __restrict__ O0, const short* __restrict__ O1,
    const short* __restrict__ O2, const short* __restrict__ O3,
    const float* __restrict__ ML, const float* __restrict__ gamma,
    const float* __restrict__ t2, const short* __restrict__ Qb,
    short* __restrict__ AOb, float* __restrict__ partials,
    short* __restrict__ Xf) {
  __shared__ __align__(16) short tileT[64][64];  // [dd][m], chunk-swizzled
  __shared__ f32x4 wcol[64];                     // per-column merge coeffs
  int tid = threadIdx.x;
  int b = blockIdx.y, kc = blockIdx.x;
  int h = kc >> 5, n0 = (kc & 31) * 64;
  int bh = (b << 2) + h;
  float g = gamma[0];
  // phase 1: per-column combine coefficients
  if (tid < 64) {
    const float* ml = ML + ((size_t)bh * NSEQ + n0 + tid) * 8;
    f32x4 a = *(const f32x4*)ml;  // m0,s0,m1,s1
    f32x4 c;
    if (NS == 2) {
      float M = fmaxf(a[0], a[2]);
      float w0 = a[1] * __builtin_amdgcn_exp2f(a[0] - M);
      float w1 = a[3] * __builtin_amdgcn_exp2f(a[2] - M);
      float iv = __builtin_amdgcn_rcpf(w0 + w1);
      c[0] = w0 * iv; c[1] = w1 * iv; c[2] = 0.f; c[3] = 0.f;
    } else {
      f32x4 bq = *(const f32x4*)(ml + 4);  // m2,s2,m3,s3
      float M = fmaxf(fmaxf(a[0], a[2]), fmaxf(bq[0], bq[2]));
      float w0 = a[1] * __builtin_amdgcn_exp2f(a[0] - M);
      float w1 = a[3] * __builtin_amdgcn_exp2f(a[2] - M);
      float w2 = bq[1] * __builtin_amdgcn_exp2f(bq[0] - M);
      float w3 = bq[3] * __builtin_amdgcn_exp2f(bq[2] - M);
      float iv = __builtin_amdgcn_rcpf(w0 + w1 + w2 + w3);
      c[0] = w0 * iv; c[1] = w1 * iv; c[2] = w2 * iv; c[3] = w3 * iv;
    }
    wcol[tid] = c;
  }
  __syncthreads();
  // phase 2: combine; 8 lanes cover one row's 128B contiguously; 2 row passes
  {
    int chunk = tid & 7;    // 16B chunk within 64-col row (8 bf16)
    int rw = tid >> 3;      // 0..31
#pragma unroll
    for (int i = 0; i < 2; i++) {
      int row = rw + 32 * i;
      size_t gbase = ((size_t)bh * 64 + row) * NSEQ + n0 + chunk * 8;
      short8_t v0 = *(const short8_t*)(O0 + gbase);
      short8_t v1 = *(const short8_t*)(O1 + gbase);
      short8_t v2{}, v3{};
      if (NS == 4) {
        v2 = *(const short8_t*)(O2 + gbase);
        v3 = *(const short8_t*)(O3 + gbase);
      }
      short8_t comb;
#pragma unroll
      for (int j = 0; j < 8; j++) {
        f32x4 c = wcol[chunk * 8 + j];
        float val = bf2f(v0[j]) * c[0] + bf2f(v1[j]) * c[1];
        if (NS == 4) val += bf2f(v2[j]) * c[2] + bf2f(v3[j]) * c[3];
        comb[j] = f2bf_hw(val);
      }
      if (g != 0.f) *(short8_t*)(AOb + gbase) = comb;
      *(short8_t*)&tileT[row][(chunk ^ (row & 7)) * 8] = comb;
    }
  }
  __syncthreads();
  if (g == 0.f) {
    // phase 3 fast path: Xf[b][n][h*64+dd] = t2 + x + q  (lam term is 0)
    int nc = tid >> 2, quarter = tid & 3;
    int n = n0 + nc;
    int cidx = nc >> 3, jj = nc & 7;
    const float* t2p = t2 + ((size_t)b * NSEQ + n) * 256 + h * 64 + quarter * 16;
    const short* qp = Qb + ((size_t)bh * NSEQ + n) * 64 + quarter * 16;
    short* xfp = Xf + ((size_t)b * NSEQ + n) * 256 + h * 64 + quarter * 16;
#pragma unroll
    for (int i = 0; i < 2; i++) {
      int ddb = quarter * 16 + i * 8;
      f32x4 ta = *(const f32x4*)(t2p + i * 8);
      f32x4 tb = *(const f32x4*)(t2p + i * 8 + 4);
      short8_t q8 = *(const short8_t*)(qp + i * 8);
      short8_t r;
#pragma unroll
      for (int j = 0; j < 8; j++) {
        int dd = ddb + j;
        short xv = tileT[dd][((cidx ^ (dd & 7)) * 8) + jj];
        float t = (j < 4) ? ta[j] : tb[j - 4];
        r[j] = f2bf_hw(t + bf2f(xv) + bf2f(q8[j]));
      }
      *(short8_t*)(xfp + i * 8) = r;
    }
    return;
  }
  // gamma != 0: energy partials via MFMA (K = 64 m -> 2 slices of 32)
  int w = tid >> 6, lr = tid & 15, lg = (tid & 63) >> 4;
  f32x4 acc[4] = {};
#pragma unroll
  for (int ks = 0; ks < 2; ks++) {
    short8_t af = *(const short8_t*)&tileT[w * 16 + lr][(((ks * 4 + lg) ^ (lr & 7)) * 8)];
#pragma unroll
    for (int e = 0; e < 4; e++) {
      short8_t bf = *(const short8_t*)&tileT[e * 16 + lr][(((ks * 4 + lg) ^ (lr & 7)) * 8)];
      acc[e] = __builtin_amdgcn_mfma_f32_16x16x32_bf16(af, bf, acc[e], 0, 0, 0);
    }
  }
  float* dst = partials + ((size_t)b * 128 + kc) * 4096;
#pragma unroll
  for (int e = 0; e < 4; e++)
#pragma unroll
    for (int r = 0; r < 4; r++)
      dst[(w * 16 + lg * 4 + r) * 64 + e * 16 + lr] = acc[e][r];
}

// -------------------------------- reduce partials over kc + channel softmax
__global__ __launch_bounds__(64) void energy_reduce_softmax(
    const float* __restrict__ partials, const float* __restrict__ gamma,
    float* __restrict__ attnc) {
  if (gamma[0] == 0.f) return;  // attnc unread when gamma == 0
  int row = blockIdx.x;  // b*64 + d
  int b = row >> 6, d = row & 63;
  int e = threadIdx.x;
  const float* src = partials + (size_t)b * 128 * 4096 + d * 64 + e;
  float s = 0.f;
#pragma unroll 8
  for (int kc = 0; kc < 128; kc++) s += src[(size_t)kc * 4096];
  float mx = s;
#pragma unroll
  for (int x = 1; x < 64; x <<= 1) mx = fmaxf(mx, __shfl_xor(mx, x, 64));
  float ev = __expf(s - mx);
  float sum = ev;
#pragma unroll
  for (int x = 1; x < 64; x <<= 1) sum += __shfl_xor(sum, x, 64);
  attnc[row * 64 + e] = ev / sum;
}

// ----------------------- lam apply + residuals (gamma != 0 slow path only)
__global__ __launch_bounds__(256) void assemble_x(
    const short* __restrict__ AOb, const float* __restrict__ attnc,
    const float* __restrict__ t2, const short* __restrict__ Qb,
    const float* __restrict__ gamma, short* __restrict__ Xf) {
  float g = gamma[0];
  if (g == 0.f) return;  // Xf already written by combine_xf fast path
  __shared__ f32x4 At4[1024];
  int b = blockIdx.y, tid = threadIdx.x;
  const f32x4* ac = (const f32x4*)(attnc + (size_t)b * 4096);
#pragma unroll
  for (int i = 0; i < 4; i++) At4[i * 256 + tid] = ac[i * 256 + tid];
  __syncthreads();
  int rowb = blockIdx.x * 256 + tid;
  int h = rowb >> 11, n = rowb & 2047;
  const short* xop = AOb + ((size_t)((b << 2) + h) * 64) * NSEQ + n;
  f32x4 xv[16];
#pragma unroll
  for (int i = 0; i < 16; i++) {
    f32x4 t;
    t[0] = bf2f(xop[(size_t)(4 * i + 0) * NSEQ]);
    t[1] = bf2f(xop[(size_t)(4 * i + 1) * NSEQ]);
    t[2] = bf2f(xop[(size_t)(4 * i + 2) * NSEQ]);
    t[3] = bf2f(xop[(size_t)(4 * i + 3) * NSEQ]);
    xv[i] = t;
  }
  const short* qp = Qb + ((size_t)b * 8192 + rowb) * 64;
  const float* t2p = t2 + ((size_t)b * 2048 + n) * 256 + h * 64;
  short* xfp = Xf + ((size_t)b * 2048 + n) * 256 + h * 64;
#pragma unroll
  for (int dd = 0; dd < 64; dd++) {
    f32x4 a = {0.f, 0.f, 0.f, 0.f};
#pragma unroll
    for (int j = 0; j < 16; j++) a += At4[dd * 16 + j] * xv[j];
    float o = (a[0] + a[1] + a[2] + a[3]) * g;
    float val = t2p[dd] + o + xv[dd >> 2][dd & 3] + bf2f(qp[dd]);
    xfp[dd] = f2bf_hw(val);
  }
}

// ------------------- final projection + bias (LDS-staged A, 16 rows/block)
__global__ __launch_bounds__(256) void gemm_proj(
    const short* __restrict__ Xf, const short* __restrict__ Wpt,
    const float* __restrict__ bias, float* __restrict__ out) {
  __shared__ __align__(16) short ldsA[16 * 256];  // 8 KB, chunk-swizzled
  int tid = threadIdx.x;
  int w = tid >> 6, l = tid & 63, lr = l & 15, lg = l >> 4;
  int m0 = blockIdx.x * 16;
#pragma unroll
  for (int i = 0; i < 2; i++) {
    int c = w * 128 + i * 64 + l;  // LDS chunk id (16B units)
    int row = c >> 5, ch = c & 31;
    int chs = (ch & 24) | ((ch & 7) ^ (row & 7));
    gload_lds16(Xf + (size_t)(m0 + row) * 256 + chs * 8,
                &ldsA[(w * 128 + i * 64) * 8]);
  }
  asm volatile("s_waitcnt vmcnt(0)" ::: "memory");
  __syncthreads();
  short8_t af[8];
#pragma unroll
  for (int ks = 0; ks < 8; ks++)
    af[ks] = *(const short8_t*)&ldsA[lr * 256 + (((ks * 4 + lg) ^ (lr & 7)) * 8)];
  f32x4 acc[4] = {};
#pragma unroll
  for (int ct = 0; ct < 4; ct++) {
    const short* br = Wpt + (size_t)(w * 64 + ct * 16 + lr) * 256 + lg * 8;
    short8_t bfr[8];
#pragma unroll
    for (int ks = 0; ks < 8; ks++) bfr[ks] = *(const short8_t*)(br + ks * 32);
#pragma unroll
    for (int ks = 0; ks < 8; ks++)
      acc[ct] = __builtin_amdgcn_mfma_f32_16x16x32_bf16(af[ks], bfr[ks], acc[ct], 0, 0, 0);
  }
#pragma unroll
  for (int ct = 0; ct < 4; ct++) {
    int c = w * 64 + ct * 16 + lr;
    float bc = bias[c];
#pragma unroll
    for (int r = 0; r < 4; r++) {
      int m = m0 + lg * 4 + r;
      out[(size_t)m * 256 + c] = acc[ct][r] + bc;
    }
  }
}

extern "C" void kernel_launch(void* const* d_in, const int* in_sizes, int n_in,
                              void* d_out, int out_size, void* d_ws, size_t ws_size,
                              hipStream_t stream) {
  const float* t2 = (const float*)d_in[0];
  const float* t1 = (const float*)d_in[1];
  const float* Wq = (const float*)d_in[2];
  const float* Wkv = (const float*)d_in[3];
  const float* Wp = (const float*)d_in[4];
  const float* bproj = (const float*)d_in[5];
  const float* gamma = (const float*)d_in[6];
  float* out = (float*)d_out;
  char* ws = (char*)d_ws;

  const size_t MB = 1024ull * 1024ull;
  short* Qb = (short*)(ws + 0);
  short* Kb = (short*)(ws + 4 * MB);
  short* Vt = (short*)(ws + 8 * MB);
  short* AOb = (short*)(ws + 8 * MB);       // aliases Vt (dead after flash)
  short* Xf = (short*)(ws + 12 * MB);
  short* O0 = (short*)(ws + 16 * MB);
  short* O1 = (short*)(ws + 20 * MB);
  short* Wqt = (short*)(ws + 24 * MB);
  short* Wkvt = (short*)(ws + 24 * MB + 128 * 1024);
  short* Wpt = (short*)(ws + 24 * MB + 384 * 1024);
  float* attnc = (float*)(ws + 24 * MB + 512 * 1024);
  float* ML = (float*)(ws + 24 * MB + 576 * 1024);  // 1 MB
  short* O2 = (short*)(ws + 26 * MB);
  short* O3 = (short*)(ws + 30 * MB);
  float* partials = (float*)(ws + 40 * MB);  // [4][128][4096] f32 = 8.4 MB

  bool big = ws_size >= 64 * MB;

  wconv<<<1024, 256, 0, stream>>>(Wq, Wkv, Wp, Wqt, Wkvt, Wpt);
  gemm_qkv3<<<dim3(256, 3), 256, 0, stream>>>(t2, t1, Wqt, Wkvt, Qb, Kb, Vt);
  if (big) {
    flash_attn_split<4><<<1024, 256, 0, stream>>>(Qb, Kb, Vt, O0, O1, O2, O3,
                                                  ML);
    combine_xf<4><<<dim3(128, 4), 256, 0, stream>>>(
        O0, O1, O2, O3, ML, gamma, t2, Qb, AOb, partials, Xf);
  } else {
    flash_attn_split<2><<<512, 256, 0, stream>>>(Qb, Kb, Vt, O0, O1, O1, O1,
                                                 ML);
    combine_xf<2><<<dim3(128, 4), 256, 0, stream>>>(
        O0, O1, O1, O1, ML, gamma, t2, Qb, AOb, partials, Xf);
  }
  energy_reduce_softmax<<<256, 64, 0, stream>>>(partials, gamma, attnc);
  assemble_x<<<dim3(32, 4), 256, 0, stream>>>(AOb, attnc, t2, Qb, gamma, Xf);
  gemm_proj<<<512, 256, 0, stream>>>(Xf, Wpt, bproj, out);
}